// Round 1
// 427.819 us; speedup vs baseline: 1.1258x; 1.1258x over previous
//
#include <hip/hip_runtime.h>
#include <hip/hip_bf16.h>
#include <math.h>

#define NTOK   16384
#define DM     768
#define DF     3072
#define NEXP   4
#define TILE_SH (128 * 32)   // shorts per LDS tile buffer (A or B), BK=32

// prep kernel flat-grid section sizes
#define XBLKS  6144                    // (NTOK*DM)/(256*8)
#define W1BLKS 2304                    // 4 * (DF/64) * (DM/64) = 4*48*12
#define W2BLKS 2304                    // 4 * (DM/64) * (DF/64)
#define PREP_BLKS (1 + XBLKS + W1BLKS + W2BLKS)

typedef short bf16x8 __attribute__((ext_vector_type(8)));
typedef float f32x4  __attribute__((ext_vector_type(4)));

// ---------------- workspace layout (bytes) ----------------
#define WS_CNT    0u
#define WS_BASES  256u                        // bases[4] + mboff[5] (ints)
#define WS_POS    512u                        // NTOK ints            = 65536
#define WS_LIST   (512u + 65536u)             // NEXP*NTOK ints       = 262144
#define WS_XB     (WS_LIST + 262144u)         // NTOK*DM bf16         = 25165824
#define WS_W1T    (WS_XB + 25165824u)         // 4*DF*DM bf16         = 18874368
#define WS_W2T    (WS_W1T + 18874368u)        // 4*DM*DF bf16         = 18874368
#define WS_H1     (WS_W2T + 18874368u)        // NTOK*DF bf16         = 100663296
#define WS_H2     (WS_H1 + 100663296u)        // NTOK*DM bf16         = 25165824
#define WS_END    (WS_H2 + 25165824u)

// ---------------- bf16 helpers (manual, RNE) ----------------
__device__ __forceinline__ ushort f2bf(float f) {
    unsigned int v; __builtin_memcpy(&v, &f, 4);
    v = v + 0x7fffu + ((v >> 16) & 1u);
    return (ushort)(v >> 16);
}
__device__ __forceinline__ float bf2f(ushort u) {
    unsigned int v = ((unsigned int)u) << 16;
    float f; __builtin_memcpy(&f, &v, 4); return f;
}

// fast gelu: x * sigmoid(1.5957691(x + 0.044715 x^3)); exp2-based, ~1e-3 abs err
__device__ __forceinline__ float fast_gelu(float v) {
    float y = v + 0.044715f * v * v * v;
    float e = __builtin_amdgcn_exp2f(-2.3022082f * y);
    return v * __builtin_amdgcn_rcpf(1.0f + e);
}

// async global->LDS, 16B per lane. LDS dest must be uniform_base + lane*16.
typedef __attribute__((address_space(1))) const void gvoid_t;
typedef __attribute__((address_space(3))) void lvoid_t;
__device__ __forceinline__ void cp16(const void* g, void* l) {
    __builtin_amdgcn_global_load_lds((gvoid_t*)g, (lvoid_t*)l, 16, 0, 0);
}

// bijective chunked XCD remap over T active blocks (m204 formula):
// hw-consecutive ids id%8==x land on XCD x (round-robin heuristic); remap so
// each XCD owns a CONTIGUOUS range of logical tiles -> same-panel n-blocks
// share that XCD's L2.
__device__ __forceinline__ int xcd_remap(int id, int T) {
    const int q = T >> 3, r = T & 7;
    const int x = id & 7, j = id >> 3;
    return (x < r ? x * (q + 1) : r * (q + 1) + (x - r) * q) + j;
}

// ---------------- transpose tile helper (shared tile passed in) ----------------
// element (R,C) of the 64x64 tile stored at
//   tile[R*72 + (((C>>3) ^ ((R>>3)&7))<<3) + (C&7)]
// slot-XOR makes the strided read-back 2-way instead of 16-way bank conflicted.
__device__ __forceinline__ void transpose_tile(
    const float* __restrict__ src, ushort* __restrict__ dst, int R, int C,
    int bx, int by, int tid, ushort* tile /* [64][72] */) {
    const int r0 = by * 64, c0 = bx * 64;
#pragma unroll
    for (int q = 0; q < 2; ++q) {
        int li = q * 256 + tid;
        int r = li >> 3, c = (li & 7) * 8;
        const float* s = src + (size_t)(r0 + r) * C + (c0 + c);
        float4 v0 = *(const float4*)s;
        float4 v1 = *(const float4*)(s + 4);
        ushort tmp[8];
        tmp[0] = f2bf(v0.x); tmp[1] = f2bf(v0.y); tmp[2] = f2bf(v0.z); tmp[3] = f2bf(v0.w);
        tmp[4] = f2bf(v1.x); tmp[5] = f2bf(v1.y); tmp[6] = f2bf(v1.z); tmp[7] = f2bf(v1.w);
        int sw = (((c >> 3) ^ ((r >> 3) & 7)) << 3);
        *(uint4*)&tile[r * 72 + sw] = *(uint4*)tmp;
    }
    __syncthreads();
#pragma unroll
    for (int q = 0; q < 2; ++q) {
        int li = q * 256 + tid;
        int r = li >> 3, c = (li & 7) * 8;
        ushort tmp[8];
#pragma unroll
        for (int j = 0; j < 8; ++j)
            tmp[j] = tile[(c + j) * 72 +
                          ((((r >> 3) & 7) ^ (((c + j) >> 3) & 7)) << 3) + (r & 7)];
        *(uint4*)(dst + (size_t)(c0 + r) * R + (r0 + c)) = *(uint4*)tmp;
    }
}

// ---------------- prep: routing + X cvt + W1/W2 transpose, one launch ----------------
__global__ __launch_bounds__(256) void prep_kernel(
    const int* __restrict__ type_seq, const float* __restrict__ X,
    const float* __restrict__ W1, const float* __restrict__ W2,
    int* __restrict__ cnt, int* __restrict__ bases,
    int* __restrict__ pos_of, int* __restrict__ list,
    ushort* __restrict__ Xb, ushort* __restrict__ W1t, ushort* __restrict__ W2t) {
    __shared__ ushort tile[64 * 72];
    __shared__ int lcnt[NEXP];
    const int tid = threadIdx.x;
    const int bid = blockIdx.x;

    if (bid == 0) {
        // single-block routing: wave-ballot prefix + LDS atomics
        if (tid < NEXP) lcnt[tid] = 0;
        __syncthreads();
        const int lane = tid & 63;
        for (int it = 0; it < NTOK / 256; ++it) {
            int t = it * 256 + tid;
            int k = type_seq[t];
#pragma unroll
            for (int e = 0; e < NEXP; ++e) {
                unsigned long long m = __ballot(k == e + 1);
                int total = __popcll(m);
                int b = 0;
                if (lane == 0 && total) b = atomicAdd(&lcnt[e], total);
                b = __shfl(b, 0, 64);
                if (k == e + 1) {
                    int p = b + __popcll(m & ((1ull << lane) - 1ull));
                    list[e * NTOK + p] = t;
                    pos_of[t] = p;
                }
            }
        }
        __syncthreads();
        if (tid == 0) {
            int s = 0, mb = 0;
            for (int e = 0; e < NEXP; ++e) {
                cnt[e] = lcnt[e];
                bases[e] = s;
                bases[8 + e] = mb;
                s += lcnt[e];
                mb += (lcnt[e] + 127) >> 7;
            }
            bases[12] = mb;
        }
        return;
    }

    int id = bid - 1;
    if (id < XBLKS) {
        // X fp32 -> bf16
        size_t i = (size_t)(id * 256 + tid) * 8;
        float4 v0 = *(const float4*)(X + i);
        float4 v1 = *(const float4*)(X + i + 4);
        ushort tmp[8];
        tmp[0] = f2bf(v0.x); tmp[1] = f2bf(v0.y); tmp[2] = f2bf(v0.z); tmp[3] = f2bf(v0.w);
        tmp[4] = f2bf(v1.x); tmp[5] = f2bf(v1.y); tmp[6] = f2bf(v1.z); tmp[7] = f2bf(v1.w);
        *(uint4*)(Xb + i) = *(uint4*)tmp;
        return;
    }
    id -= XBLKS;
    if (id < W1BLKS) {
        // W1 [z][768][3072] -> W1t [z][3072][768]
        int z = id / 576, r = id % 576;
        size_t mb = (size_t)z * DM * DF;
        transpose_tile(W1 + mb, W1t + mb, DM, DF, r % 48, r / 48, tid, tile);
        return;
    }
    id -= W1BLKS;
    {
        // W2 [z][3072][768] -> W2t [z][768][3072]
        int z = id / 576, r = id % 576;
        size_t mb = (size_t)z * DF * DM;
        transpose_tile(W2 + mb, W2t + mb, DF, DM, r % 12, r / 12, tid, tile);
    }
}

// =====================================================================
// GEMM structure (both kernels): 512 threads = 8 waves, tile 128x128,
// BK=32, per-wave 64x32 output (4 M-frags x 2 N-frags), double-buffered
// LDS staged via global_load_lds.
// LDS k-quad swizzle (both-sides, rule #21): LDS slot (row,q) holds
// global quad q ^ ((row>>1)&3). Staged by pre-swizzling the per-thread
// GLOBAL source offset (dest stays linear = wave-uniform + lane*16);
// read side XORs the same key -> ds_read_b128 goes 8-way -> 2-way.
// =====================================================================

// ---------------- GEMM1: h1[base+i][f] = gelu( Xb[list[i]] . W1t[f][:] + b1[f] ) ----------------
// grid (24, 132) flattened+remapped, block 512
__global__ __launch_bounds__(512, 4) void gemm1_kernel(
    const ushort* __restrict__ Xb, const ushort* __restrict__ W1t,
    const float* __restrict__ b1, const int* __restrict__ cnt,
    const int* __restrict__ bases, const int* __restrict__ list,
    ushort* __restrict__ h1) {
    const int mb = bases[12];
    const int T = mb * 24;
    int id = blockIdx.y * 24 + blockIdx.x;
    if (id >= T) return;
    id = xcd_remap(id, T);
    const int y = id / 24;
    const int n0 = (id % 24) * 128;
    const int* mboff = bases + 8;
    const int e = (y >= mboff[1]) + (y >= mboff[2]) + (y >= mboff[3]);
    const int m0 = (y - mboff[e]) << 7;
    const int count = cnt[e];
    const int NK = DM / 32;

    __shared__ __align__(16) short As[2 * TILE_SH];
    __shared__ __align__(16) short Bs[2 * TILE_SH];

    const int tid = threadIdx.x;
    const int wave = tid >> 6, lane = tid & 63;
    const int wm = (wave & 1) * 64, wn = (wave >> 1) * 32;
    const int lrow = lane & 15;
    const int qg = lane >> 4;

    int r0 = min(m0 + (tid >> 2), count - 1);
    int t0 = list[e * NTOK + r0];
    const int qsrc = ((tid & 3) ^ ((tid >> 3) & 3)) * 8;   // source k-quad pre-swizzle
    const ushort* a0 = Xb + (size_t)t0 * DM + qsrc;
    const ushort* Wb = W1t + (size_t)e * DF * DM;
    const ushort* bp0 = Wb + (size_t)(n0 + (tid >> 2)) * DM + qsrc;

    short* aDst = As + tid * 8;
    short* bDst = Bs + tid * 8;

    int aOff[4], bOff[2];
#pragma unroll
    for (int i = 0; i < 4; ++i) {
        int ra = wm + i * 16 + lrow;
        aOff[i] = ra * 32 + (qg ^ ((ra >> 1) & 3)) * 8;
    }
#pragma unroll
    for (int j = 0; j < 2; ++j) {
        int rb = wn + j * 16 + lrow;
        bOff[j] = rb * 32 + (qg ^ ((rb >> 1) & 3)) * 8;
    }

    f32x4 z = {0.f, 0.f, 0.f, 0.f};
    f32x4 acc[4][2];
#pragma unroll
    for (int i = 0; i < 4; ++i)
#pragma unroll
        for (int j = 0; j < 2; ++j) acc[i][j] = z;

    cp16(a0, aDst); cp16(bp0, bDst);
    a0 += 32; bp0 += 32;

    for (int ks = 0; ks < NK; ++ks) {
        __syncthreads();
        const int nsel = ((ks + 1) & 1) * TILE_SH;
        if (ks + 1 < NK) {
            cp16(a0, aDst + nsel); cp16(bp0, bDst + nsel);
            a0 += 32; bp0 += 32;
        }
        const short* Ab = As + (ks & 1) * TILE_SH;
        const short* Bb = Bs + (ks & 1) * TILE_SH;
        bf16x8 av[4], bv[2];
#pragma unroll
        for (int i = 0; i < 4; ++i) av[i] = *(const bf16x8*)(Ab + aOff[i]);
#pragma unroll
        for (int j = 0; j < 2; ++j) bv[j] = *(const bf16x8*)(Bb + bOff[j]);
#pragma unroll
        for (int i = 0; i < 4; ++i)
#pragma unroll
            for (int j = 0; j < 2; ++j)
                acc[i][j] = __builtin_amdgcn_mfma_f32_16x16x32_bf16(av[i], bv[j], acc[i][j], 0, 0, 0);
    }

    const int base = bases[e];
    float bias[2];
#pragma unroll
    for (int nt = 0; nt < 2; ++nt)
        bias[nt] = b1[e * DF + n0 + wn + nt * 16 + lrow];
#pragma unroll
    for (int mt = 0; mt < 4; ++mt) {
        int gm = m0 + wm + mt * 16 + (lane >> 4) * 4;
#pragma unroll
        for (int nt = 0; nt < 2; ++nt) {
            int gn = n0 + wn + nt * 16 + lrow;
#pragma unroll
            for (int r = 0; r < 4; ++r) {
                int i = gm + r;
                if (i < count) {
                    float v = acc[mt][nt][r] + bias[nt];
                    h1[(size_t)(base + i) * DF + gn] = f2bf(fast_gelu(v));
                }
            }
        }
    }
}

// ---------------- GEMM2: h2[base+i][h] = h1[base+i] . W2t[h][:] + b2[h] ----------------
// grid (6, 132) flattened+remapped, block 512
__global__ __launch_bounds__(512, 4) void gemm2_kernel(
    const ushort* __restrict__ h1, const ushort* __restrict__ W2t,
    const float* __restrict__ b2, const int* __restrict__ cnt,
    const int* __restrict__ bases, ushort* __restrict__ h2) {
    const int mb = bases[12];
    const int T = mb * 6;
    int id = blockIdx.y * 6 + blockIdx.x;
    if (id >= T) return;
    id = xcd_remap(id, T);
    const int y = id / 6;
    const int n0 = (id % 6) * 128;
    const int* mboff = bases + 8;
    const int e = (y >= mboff[1]) + (y >= mboff[2]) + (y >= mboff[3]);
    const int m0 = (y - mboff[e]) << 7;
    const int count = cnt[e];
    const int base = bases[e];
    const int NK = DF / 32;

    __shared__ __align__(16) short As[2 * TILE_SH];
    __shared__ __align__(16) short Bs[2 * TILE_SH];

    const int tid = threadIdx.x;
    const int wave = tid >> 6, lane = tid & 63;
    const int wm = (wave & 1) * 64, wn = (wave >> 1) * 32;
    const int lrow = lane & 15;
    const int qg = lane >> 4;

    int r0 = min(m0 + (tid >> 2), count - 1);
    const int qsrc = ((tid & 3) ^ ((tid >> 3) & 3)) * 8;
    const ushort* a0 = h1 + (size_t)(base + r0) * DF + qsrc;
    const ushort* Wb = W2t + (size_t)e * DM * DF;
    const ushort* bp0 = Wb + (size_t)(n0 + (tid >> 2)) * DF + qsrc;

    short* aDst = As + tid * 8;
    short* bDst = Bs + tid * 8;

    int aOff[4], bOff[2];
#pragma unroll
    for (int i = 0; i < 4; ++i) {
        int ra = wm + i * 16 + lrow;
        aOff[i] = ra * 32 + (qg ^ ((ra >> 1) & 3)) * 8;
    }
#pragma unroll
    for (int j = 0; j < 2; ++j) {
        int rb = wn + j * 16 + lrow;
        bOff[j] = rb * 32 + (qg ^ ((rb >> 1) & 3)) * 8;
    }

    f32x4 z = {0.f, 0.f, 0.f, 0.f};
    f32x4 acc[4][2];
#pragma unroll
    for (int i = 0; i < 4; ++i)
#pragma unroll
        for (int j = 0; j < 2; ++j) acc[i][j] = z;

    cp16(a0, aDst); cp16(bp0, bDst);
    a0 += 32; bp0 += 32;

    for (int ks = 0; ks < NK; ++ks) {
        __syncthreads();
        const int nsel = ((ks + 1) & 1) * TILE_SH;
        if (ks + 1 < NK) {
            cp16(a0, aDst + nsel); cp16(bp0, bDst + nsel);
            a0 += 32; bp0 += 32;
        }
        const short* Ab = As + (ks & 1) * TILE_SH;
        const short* Bb = Bs + (ks & 1) * TILE_SH;
        bf16x8 av[4], bv[2];
#pragma unroll
        for (int i = 0; i < 4; ++i) av[i] = *(const bf16x8*)(Ab + aOff[i]);
#pragma unroll
        for (int j = 0; j < 2; ++j) bv[j] = *(const bf16x8*)(Bb + bOff[j]);
#pragma unroll
        for (int i = 0; i < 4; ++i)
#pragma unroll
            for (int j = 0; j < 2; ++j)
                acc[i][j] = __builtin_amdgcn_mfma_f32_16x16x32_bf16(av[i], bv[j], acc[i][j], 0, 0, 0);
    }

    float bias[2];
#pragma unroll
    for (int nt = 0; nt < 2; ++nt)
        bias[nt] = b2[e * DM + n0 + wn + nt * 16 + lrow];
#pragma unroll
    for (int mt = 0; mt < 4; ++mt) {
        int gm = m0 + wm + mt * 16 + (lane >> 4) * 4;
#pragma unroll
        for (int nt = 0; nt < 2; ++nt) {
            int gn = n0 + wn + nt * 16 + lrow;
#pragma unroll
            for (int r = 0; r < 4; ++r) {
                int i = gm + r;
                if (i < count)
                    h2[(size_t)(base + i) * DM + gn] = f2bf(acc[mt][nt][r] + bias[nt]);
            }
        }
    }
}

// ---------------- finalize ----------------
__device__ __forceinline__ void block_reduce2(float& a, float& b, float* sm, int tid) {
    __syncthreads();
#pragma unroll
    for (int off = 32; off > 0; off >>= 1) {
        a += __shfl_down(a, off, 64);
        b += __shfl_down(b, off, 64);
    }
    const int wave = tid >> 6, lane = tid & 63;
    if (lane == 0) { sm[wave] = a; sm[4 + wave] = b; }
    __syncthreads();
    a = sm[0] + sm[1] + sm[2] + sm[3];
    b = sm[4] + sm[5] + sm[6] + sm[7];
}

__global__ __launch_bounds__(256) void finalize_kernel(
    const float* __restrict__ X, const int* __restrict__ type_seq,
    const int* __restrict__ pos_of, const int* __restrict__ bases,
    const ushort* __restrict__ h2,
    const float* __restrict__ ln_g, const float* __restrict__ ln_b,
    const float* __restrict__ out_g, const float* __restrict__ out_b,
    float* __restrict__ out) {
    __shared__ float sm[8];
    const int t = blockIdx.x;
    const int tid = threadIdx.x;
    const int k = type_seq[t];

    float xv[3], rv[3];
#pragma unroll
    for (int j = 0; j < 3; ++j) xv[j] = X[(size_t)t * DM + j * 256 + tid];

    if (k > 0) {
        const int e = k - 1;
        const size_t row = (size_t)(bases[e] + pos_of[t]);
        float v[3], s1 = 0.f, s2 = 0.f;
#pragma unroll
        for (int j = 0; j < 3; ++j) {
            v[j] = bf2f(h2[row * DM + j * 256 + tid]) + xv[j];
            s1 += v[j]; s2 += v[j] * v[j];
        }
        block_reduce2(s1, s2, sm, tid);
        float m = s1 * (1.f / DM);
        float inv = rsqrtf(s2 * (1.f / DM) - m * m + 1e-12f);
#pragma unroll
        for (int j = 0; j < 3; ++j) {
            int c = j * 256 + tid;
            rv[j] = (v[j] - m) * inv * ln_g[e * DM + c] + ln_b[e * DM + c];
        }
    } else {
        rv[0] = rv[1] = rv[2] = 0.f;
    }

    float w[3], s1 = 0.f, s2 = 0.f;
#pragma unroll
    for (int j = 0; j < 3; ++j) {
        w[j] = rv[j] + xv[j];
        s1 += w[j]; s2 += w[j] * w[j];
    }
    block_reduce2(s1, s2, sm, tid);
    float m = s1 * (1.f / DM);
    float inv = rsqrtf(s2 * (1.f / DM) - m * m + 1e-12f);
#pragma unroll
    for (int j = 0; j < 3; ++j) {
        int c = j * 256 + tid;
        out[(size_t)t * DM + c] = (w[j] - m) * inv * out_g[c] + out_b[c];
    }
}

// ---------------- launcher ----------------
extern "C" void kernel_launch(void* const* d_in, const int* in_sizes, int n_in,
                              void* d_out, int out_size, void* d_ws, size_t ws_size,
                              hipStream_t stream) {
    if (ws_size < (size_t)WS_END) return;

    const float* X     = (const float*)d_in[0];
    const int*   type  = (const int*)d_in[1];
    const float* W1    = (const float*)d_in[2];
    const float* b1    = (const float*)d_in[3];
    const float* W2    = (const float*)d_in[4];
    const float* b2    = (const float*)d_in[5];
    const float* ln_g  = (const float*)d_in[6];
    const float* ln_b  = (const float*)d_in[7];
    const float* out_g = (const float*)d_in[8];
    const float* out_b = (const float*)d_in[9];
    float* out = (float*)d_out;

    char* ws = (char*)d_ws;
    int* cnt    = (int*)(ws + WS_CNT);
    int* bases  = (int*)(ws + WS_BASES);
    int* pos_of = (int*)(ws + WS_POS);
    int* list   = (int*)(ws + WS_LIST);
    ushort* Xb  = (ushort*)(ws + WS_XB);
    ushort* W1t = (ushort*)(ws + WS_W1T);
    ushort* W2t = (ushort*)(ws + WS_W2T);
    ushort* h1  = (ushort*)(ws + WS_H1);
    ushort* h2  = (ushort*)(ws + WS_H2);

    prep_kernel<<<PREP_BLKS, 256, 0, stream>>>(type, X, W1, W2,
                                               cnt, bases, pos_of, list, Xb, W1t, W2t);
    gemm1_kernel<<<dim3(DF / 128, 132), 512, 0, stream>>>(Xb, W1t, b1, cnt, bases, list, h1);
    gemm2_kernel<<<dim3(DM / 128, 132), 512, 0, stream>>>(h1, W2t, b2, cnt, bases, h2);
    finalize_kernel<<<NTOK, 256, 0, stream>>>(X, type, pos_of, bases, h2, ln_g, ln_b, out_g, out_b, out);
}